// Round 2
// baseline (3822.678 us; speedup 1.0000x reference)
//
#include <hip/hip_runtime.h>
#include <math.h>

#define BB 32
#define TT 2048
#define HH 128

// Lightweight barrier: waits LDS ops only (lgkmcnt), leaves global loads/
// stores in flight across the barrier. __syncthreads() would drain vmcnt(0)
// every step, serializing the L2-latency prefetch into the critical path.
#define LDS_BARRIER() asm volatile("s_waitcnt lgkmcnt(0)\n\ts_barrier" ::: "memory")

// ---------------------------------------------------------------------------
// proj kernel: out[r, :] = src_row(r) @ W + bias
//   GATHER=true : src_row(r) = emb[tokens[r]]
//   GATHER=false: src_row(r) = src[r]
// ---------------------------------------------------------------------------
template <bool GATHER>
__global__ __launch_bounds__(256) void proj_kernel(
    const float* __restrict__ src, const int* __restrict__ tokens,
    const float* __restrict__ W, const float* __restrict__ bias,
    float* __restrict__ out) {
  const int tid = threadIdx.x;
  const int jj = tid & 31;
  const int rr = tid >> 5;
  const int base = blockIdx.x * 64;

  __shared__ __align__(16) float srow[64][HH];
  __shared__ int stok[64];

  if (GATHER) {
    if (tid < 64) stok[tid] = tokens[base + tid];
    __syncthreads();
  }

#pragma unroll
  for (int i = 0; i < 8; ++i) {
    int idx = tid + i * 256;
    int row = idx >> 5;
    int c4 = idx & 31;
    const float* s = GATHER ? (src + (size_t)stok[row] * HH)
                            : (src + (size_t)(base + row) * HH);
    *(float4*)&srow[row][c4 * 4] = *(const float4*)&s[c4 * 4];
  }
  __syncthreads();

  float4 b4 = *(const float4*)&bias[jj * 4];
  float4 acc[8];
#pragma unroll
  for (int i = 0; i < 8; ++i) acc[i] = b4;

  for (int k = 0; k < HH; ++k) {
    float4 w4 = *(const float4*)&W[k * HH + jj * 4];
#pragma unroll
    for (int i = 0; i < 8; ++i) {
      float e = srow[rr * 8 + i][k];
      acc[i].x += e * w4.x;
      acc[i].y += e * w4.y;
      acc[i].z += e * w4.z;
      acc[i].w += e * w4.w;
    }
  }

#pragma unroll
  for (int i = 0; i < 8; ++i) {
    int row = base + rr * 8 + i;
    *(float4*)&out[(size_t)row * HH + jj * 4] = acc[i];
  }
}

// ---------------------------------------------------------------------------
// rnn kernel: in-place recurrence, one block (128 thr / 2 waves) per batch.
//   h_t = mask_t ? tanh(xp_t + h_{t-1} @ Wh) : h_{t-1}
// Wh column j in 128 VGPRs of thread j. h broadcast via double-buffered LDS,
// ONE lgkmcnt-only barrier per step. Mask held as a per-lane 32-bit word
// (lane l covers t in [32l, 32l+32)) -> v_readlane per step, no memory.
// xp prefetched distance-4 (in-place safe: reads [t+4], writes [t]; all
// global accesses of thread j touch only column j -> no cross-thread alias).
// ---------------------------------------------------------------------------
__global__ __launch_bounds__(128) void rnn_kernel(
    float* io, const float* __restrict__ Wh, const int* __restrict__ tokens) {
  const int b = blockIdx.x;
  const int j = threadIdx.x;
  const int lane = j & 63;

  float w[HH];
#pragma unroll
  for (int k = 0; k < HH; ++k) w[k] = Wh[k * HH + j];  // column j of Wh

  // Mask bitmask: lane l holds bits for t in [32l, 32l+32).
  const int* tok = tokens + b * TT;
  unsigned bits = 0;
#pragma unroll
  for (int i = 0; i < 8; ++i) {
    int4 tk = *(const int4*)&tok[lane * 32 + i * 4];
    bits |= (unsigned)(tk.x != 0) << (i * 4 + 0);
    bits |= (unsigned)(tk.y != 0) << (i * 4 + 1);
    bits |= (unsigned)(tk.z != 0) << (i * 4 + 2);
    bits |= (unsigned)(tk.w != 0) << (i * 4 + 3);
  }

  __shared__ __align__(16) float hs[2][HH];
  hs[0][j] = 0.0f;

  float* xp = io + (size_t)b * TT * HH;

  // Distance-4 prefetch ring.
  float xpre[4];
#pragma unroll
  for (int i = 0; i < 4; ++i) xpre[i] = xp[(size_t)i * HH + j];

  float h = 0.0f;
  LDS_BARRIER();

#pragma unroll 4
  for (int t = 0; t < TT; ++t) {
    float x = xpre[t & 3];
    if (t + 4 < TT) xpre[t & 3] = xp[(size_t)(t + 4) * HH + j];

    unsigned word = __builtin_amdgcn_readlane(bits, t >> 5);
    int m = (word >> (t & 31)) & 1;

    const float* hb = hs[t & 1];
    float a0 = x, a1 = 0.0f, a2 = 0.0f, a3 = 0.0f;
#pragma unroll
    for (int k = 0; k < HH; k += 4) {
      float4 hv = *(const float4*)&hb[k];
      a0 += hv.x * w[k];
      a1 += hv.y * w[k + 1];
      a2 += hv.z * w[k + 2];
      a3 += hv.w * w[k + 3];
    }
    float acc = (a0 + a1) + (a2 + a3);

    // tanh, overflow-safe: e = exp(-2|x|) in (0,1]
    float ax = fabsf(acc);
    float e = __expf(-2.0f * ax);
    float th = (1.0f - e) * __builtin_amdgcn_rcpf(1.0f + e);
    th = copysignf(th, acc);

    h = m ? th : h;

    xp[(size_t)t * HH + j] = h;   // ys output (in-place; fire-and-forget)
    hs[(t + 1) & 1][j] = h;       // publish h for next step
    LDS_BARRIER();
  }
}

extern "C" void kernel_launch(void* const* d_in, const int* in_sizes, int n_in,
                              void* d_out, int out_size, void* d_ws,
                              size_t ws_size, hipStream_t stream) {
  const int* tokens = (const int*)d_in[0];
  const float* emb = (const float*)d_in[1];
  const float* Wx0 = (const float*)d_in[2];
  const float* Wh0 = (const float*)d_in[3];
  const float* b0 = (const float*)d_in[4];
  const float* Wx1 = (const float*)d_in[5];
  const float* Wh1 = (const float*)d_in[6];
  const float* b1 = (const float*)d_in[7];
  float* out = (float*)d_out;
  float* ws = (float*)d_ws;  // 32 MB: xp0 -> ys0 (in-place)

  const int rows = BB * TT;            // 65536
  const int proj_blocks = rows / 64;   // 1024

  proj_kernel<true><<<proj_blocks, 256, 0, stream>>>(emb, tokens, Wx0, b0, ws);
  rnn_kernel<<<BB, 128, 0, stream>>>(ws, Wh0, tokens);
  proj_kernel<false><<<proj_blocks, 256, 0, stream>>>(ws, nullptr, Wx1, b1, out);
  rnn_kernel<<<BB, 128, 0, stream>>>(out, Wh1, tokens);
}

// Round 3
// 1406.277 us; speedup vs baseline: 2.7183x; 2.7183x over previous
//
#include <hip/hip_runtime.h>
#include <math.h>

#define BB 32
#define TT 2048
#define HH 128

// LDS-only barrier: waits LDS ops (lgkmcnt), leaves global loads/stores in
// flight across the barrier.
#define LDS_BARRIER() asm volatile("s_waitcnt lgkmcnt(0)\n\ts_barrier" ::: "memory")

// DPP quad_perm helper: returns v[quad_perm] within each 4-lane quad.
// CTRL = p0 | p1<<2 | p2<<4 | p3<<6.  xor1 = 0xB1, xor2 = 0x4E, bcast q = q*0x55.
#define QPERM_F(v, CTRL)                                                      \
  __int_as_float(__builtin_amdgcn_update_dpp(                                 \
      0, __float_as_int(v), (CTRL), 0xF, 0xF, true))

// ---------------------------------------------------------------------------
// proj kernel: out[r, :] = src_row(r) @ W + bias
//   GATHER=true : src_row(r) = emb[tokens[r]]
//   GATHER=false: src_row(r) = src[r]
// ---------------------------------------------------------------------------
template <bool GATHER>
__global__ __launch_bounds__(256) void proj_kernel(
    const float* __restrict__ src, const int* __restrict__ tokens,
    const float* __restrict__ W, const float* __restrict__ bias,
    float* __restrict__ out) {
  const int tid = threadIdx.x;
  const int jj = tid & 31;
  const int rr = tid >> 5;
  const int base = blockIdx.x * 64;

  __shared__ __align__(16) float srow[64][HH];
  __shared__ int stok[64];

  if (GATHER) {
    if (tid < 64) stok[tid] = tokens[base + tid];
    __syncthreads();
  }

#pragma unroll
  for (int i = 0; i < 8; ++i) {
    int idx = tid + i * 256;
    int row = idx >> 5;
    int c4 = idx & 31;
    const float* s = GATHER ? (src + (size_t)stok[row] * HH)
                            : (src + (size_t)(base + row) * HH);
    *(float4*)&srow[row][c4 * 4] = *(const float4*)&s[c4 * 4];
  }
  __syncthreads();

  float4 b4 = *(const float4*)&bias[jj * 4];
  float4 acc[8];
#pragma unroll
  for (int i = 0; i < 8; ++i) acc[i] = b4;

  for (int k = 0; k < HH; ++k) {
    float4 w4 = *(const float4*)&W[k * HH + jj * 4];
#pragma unroll
    for (int i = 0; i < 8; ++i) {
      float e = srow[rr * 8 + i][k];
      acc[i].x += e * w4.x;
      acc[i].y += e * w4.y;
      acc[i].z += e * w4.z;
      acc[i].w += e * w4.w;
    }
  }

#pragma unroll
  for (int i = 0; i < 8; ++i) {
    int row = base + rr * 8 + i;
    *(float4*)&out[(size_t)row * HH + jj * 4] = acc[i];
  }
}

// ---------------------------------------------------------------------------
// rnn kernel v3: quad-split dot product.
// 512 threads/block, one block per batch. Thread (j = tid>>2, p = tid&3)
// holds 32 weights of Wh column j (k = 16i + 4p + r) -> 32 VGPRs, SROA-safe
// (round-2 failure: float w[128] went to scratch, VGPR_Count=84).
// Per step: 8x ds_read_b128 (conflict-free broadcast) + 32 FMA, then DPP
// quad-reduce (xor1, xor2) gives all 4 lanes the full 128-dot. x loaded once
// per 4 steps (lane p holds row t0+p), DPP quad-broadcast per step.
// h published via double-buffered LDS; one lgkm-barrier per step.
// ---------------------------------------------------------------------------
__global__ __launch_bounds__(512) void rnn_kernel(
    float* io, const float* __restrict__ Wh, const int* __restrict__ tokens) {
  const int b = blockIdx.x;
  const int tid = threadIdx.x;
  const int j = tid >> 2;    // output column 0..127
  const int p = tid & 3;     // k-split 0..3
  const int lane = tid & 63;

  // 32 weights: w[c] <-> k = 16*(c>>2) + 4*p + (c&3)
  float w[32];
#pragma unroll
  for (int c = 0; c < 32; ++c) {
    int k = 16 * (c >> 2) + 4 * p + (c & 3);
    w[c] = Wh[k * HH + j];
  }

  // Mask bitmask: lane l holds bits for t in [32l, 32l+32).
  const int* tok = tokens + b * TT;
  unsigned bits = 0;
#pragma unroll
  for (int i = 0; i < 8; ++i) {
    int4 tk = *(const int4*)&tok[lane * 32 + i * 4];
    bits |= (unsigned)(tk.x != 0) << (i * 4 + 0);
    bits |= (unsigned)(tk.y != 0) << (i * 4 + 1);
    bits |= (unsigned)(tk.z != 0) << (i * 4 + 2);
    bits |= (unsigned)(tk.w != 0) << (i * 4 + 3);
  }

  __shared__ __align__(16) float hs[2][HH];
  if (tid < HH) hs[0][tid] = 0.0f;

  float* xp = io + (size_t)b * TT * HH;

  float h = 0.0f;
  // lane p holds x for step t0+p of the current 4-step group
  float xcur = xp[(size_t)p * HH + j];
  LDS_BARRIER();

#define RNN_STEP(Q)                                                           \
  {                                                                           \
    const int t = t0 + (Q);                                                   \
    const float* hb = hs[t & 1];                                              \
    float a0 = 0.f, a1 = 0.f, a2 = 0.f, a3 = 0.f;                             \
    _Pragma("unroll") for (int i = 0; i < 8; ++i) {                           \
      float4 hv = *(const float4*)&hb[16 * i + 4 * p];                        \
      a0 += hv.x * w[4 * i + 0];                                              \
      a1 += hv.y * w[4 * i + 1];                                              \
      a2 += hv.z * w[4 * i + 2];                                              \
      a3 += hv.w * w[4 * i + 3];                                              \
    }                                                                         \
    float acc = (a0 + a1) + (a2 + a3);                                        \
    acc += QPERM_F(acc, 0xB1); /* xor 1 */                                    \
    acc += QPERM_F(acc, 0x4E); /* xor 2 */                                    \
    float x = QPERM_F(xcur, (Q)*0x55); /* quad-broadcast lane Q */            \
    float s = acc + x;                                                        \
    unsigned word =                                                           \
        (unsigned)__builtin_amdgcn_readlane((int)bits, t >> 5);               \
    int m = (word >> (t & 31)) & 1;                                           \
    float ax = fabsf(s);                                                      \
    float e = __expf(-2.0f * ax);                                             \
    float th = (1.0f - e) * __builtin_amdgcn_rcpf(1.0f + e);                  \
    th = copysignf(th, s);                                                    \
    h = m ? th : h;                                                           \
    if (p == 0) {                                                             \
      xp[(size_t)t * HH + j] = h;  /* ys output (in-place) */                 \
      hs[(t + 1) & 1][j] = h;      /* publish h */                            \
    }                                                                         \
    LDS_BARRIER();                                                            \
  }

  for (int t0 = 0; t0 < TT; t0 += 4) {
    float xnext = 0.0f;
    if (t0 + 4 < TT) xnext = xp[(size_t)(t0 + 4 + p) * HH + j];
    RNN_STEP(0)
    RNN_STEP(1)
    RNN_STEP(2)
    RNN_STEP(3)
    xcur = xnext;
  }
#undef RNN_STEP
}

extern "C" void kernel_launch(void* const* d_in, const int* in_sizes, int n_in,
                              void* d_out, int out_size, void* d_ws,
                              size_t ws_size, hipStream_t stream) {
  const int* tokens = (const int*)d_in[0];
  const float* emb = (const float*)d_in[1];
  const float* Wx0 = (const float*)d_in[2];
  const float* Wh0 = (const float*)d_in[3];
  const float* b0 = (const float*)d_in[4];
  const float* Wx1 = (const float*)d_in[5];
  const float* Wh1 = (const float*)d_in[6];
  const float* b1 = (const float*)d_in[7];
  float* out = (float*)d_out;
  float* ws = (float*)d_ws;  // 32 MB: xp0 -> ys0 (in-place)

  const int rows = BB * TT;            // 65536
  const int proj_blocks = rows / 64;   // 1024

  proj_kernel<true><<<proj_blocks, 256, 0, stream>>>(emb, tokens, Wx0, b0, ws);
  rnn_kernel<<<BB, 512, 0, stream>>>(ws, Wh0, tokens);
  proj_kernel<false><<<proj_blocks, 256, 0, stream>>>(ws, nullptr, Wx1, b1, out);
  rnn_kernel<<<BB, 512, 0, stream>>>(out, Wh1, tokens);
}